// Round 2
// baseline (7988.852 us; speedup 1.0000x reference)
//
#include <hip/hip_runtime.h>
#include <cstdint>
#include <cstddef>

#define BB 64
#define TT 512
#define II 256
#define HH 256
#define GG 768   // 3*H

__device__ __forceinline__ float sigf(float x)       { return 1.f / (1.f + __expf(-x)); }
__device__ __forceinline__ float tanh_fast(float x)  { return 1.f - 2.f / (__expf(2.f * x) + 1.f); }

// ---------------------------------------------------------------------------
// Kernel A: transpose Wh into ws:  wt[d][k][g] = Wh_d[g][k]
// ---------------------------------------------------------------------------
__global__ void transpose_wh(const float* __restrict__ Whf,
                             const float* __restrict__ Whb,
                             float* __restrict__ wt)
{
    int g = blockIdx.x * 256 + threadIdx.x;   // 0..767 (grid.x = 3)
    int k = blockIdx.y;                        // 0..255
    int d = blockIdx.z;                        // 0..1
    const float* W = d ? Whb : Whf;
    wt[((size_t)d * II + k) * GG + g] = W[(size_t)g * II + k];
}

// ---------------------------------------------------------------------------
// Kernel B: gi[d][b][t][g] = x[b,t,:] @ Wi_d[g,:] + bi_d[g]
// M = 2*B*T = 65536 rows (m = d*32768 + b*512 + t), N = 768, K = 256
// ---------------------------------------------------------------------------
__global__ __launch_bounds__(256) void gi_gemm(
    const float* __restrict__ x,
    const float* __restrict__ Wif, const float* __restrict__ bif,
    const float* __restrict__ Wib, const float* __restrict__ bib,
    float* __restrict__ gi)
{
    const int KC = 16;
    __shared__ float As[64][KC + 1];
    __shared__ float Bs[64][KC + 1];

    const int m0 = blockIdx.x * 64;
    const int n0 = blockIdx.y * 64;
    const int d  = m0 >> 15;
    const float* __restrict__ W    = d ? Wib : Wif;
    const float* __restrict__ bias = d ? bib : bif;

    const int tid = threadIdx.x;
    const int tx = tid & 15, ty = tid >> 4;
    const int xrow = m0 & 32767;

    const int le = tid * 4;
    const int lr = le >> 4;
    const int lk = le & 15;

    float acc[4][4] = {};

    for (int k0 = 0; k0 < II; k0 += KC) {
        float4 av = *(const float4*)&x[(size_t)(xrow + lr) * II + (k0 + lk)];
        float4 bv = *(const float4*)&W[(size_t)(n0 + lr) * II + (k0 + lk)];
        As[lr][lk + 0] = av.x; As[lr][lk + 1] = av.y; As[lr][lk + 2] = av.z; As[lr][lk + 3] = av.w;
        Bs[lr][lk + 0] = bv.x; Bs[lr][lk + 1] = bv.y; Bs[lr][lk + 2] = bv.z; Bs[lr][lk + 3] = bv.w;
        __syncthreads();
#pragma unroll
        for (int kk = 0; kk < KC; ++kk) {
            float a[4], b[4];
#pragma unroll
            for (int i = 0; i < 4; ++i) a[i] = As[ty * 4 + i][kk];
#pragma unroll
            for (int j = 0; j < 4; ++j) b[j] = Bs[tx * 4 + j][kk];
#pragma unroll
            for (int i = 0; i < 4; ++i)
#pragma unroll
                for (int j = 0; j < 4; ++j) acc[i][j] += a[i] * b[j];
        }
        __syncthreads();
    }

#pragma unroll
    for (int i = 0; i < 4; ++i) {
        float4 o;
        o.x = acc[i][0] + bias[n0 + tx * 4 + 0];
        o.y = acc[i][1] + bias[n0 + tx * 4 + 1];
        o.z = acc[i][2] + bias[n0 + tx * 4 + 2];
        o.w = acc[i][3] + bias[n0 + tx * 4 + 3];
        *(float4*)&gi[(size_t)(m0 + ty * 4 + i) * GG + n0 + tx * 4] = o;
    }
}

// ---------------------------------------------------------------------------
// Kernel C (new): register-resident recurrent weights.
// One WG per (direction, batch) chain; 768 threads = 12 waves.
// Thread g holds Wh row g as 128 packed-bf16x2 VGPRs (256 weights).
// h broadcast from LDS via wave-uniform ds_read_b128; gi prefetched 1 step
// ahead into a register. Per step: 256 FMA + 256 unpack VALU ops/thread.
// __launch_bounds__(768,3): 12 waves need 3 waves/SIMD -> VGPR cap 170.
// ---------------------------------------------------------------------------
__global__ __launch_bounds__(768, 3) void gru_scan_reg(
    const float* __restrict__ gi,     // [2][B][T][G] fp32
    const float* __restrict__ wt,     // [2][K=256][G=768] transposed Wh
    const float* __restrict__ h0f, const float* __restrict__ h0b,
    const float* __restrict__ bhf, const float* __restrict__ bhb,
    float* __restrict__ out)
{
    __shared__ __align__(16) float hbuf[2][HH];
    __shared__ float gh_s[GG];
    __shared__ float gi_s[GG];

    const int bx  = blockIdx.x;
    const int d   = bx >> 6;
    const int b   = bx & 63;
    const int tid = threadIdx.x;

    const float* __restrict__ bh = d ? bhb : bhf;
    const float* __restrict__ h0 = d ? h0b : h0f;

    if (tid < HH) hbuf[0][tid] = h0[(size_t)b * HH + tid];

    // ---- pack Wh row `tid` into 128 bf16x2 registers (coalesced via wt) ----
    const float* __restrict__ wtd = wt + (size_t)d * II * GG + tid;
    uint32_t w[128];
#pragma unroll
    for (int j = 0; j < 128; ++j) {
        uint32_t ua = __float_as_uint(wtd[(size_t)(2 * j) * GG]);
        uint32_t ub = __float_as_uint(wtd[(size_t)(2 * j + 1) * GG]);
        ua = (ua + 0x7fffu + ((ua >> 16) & 1u)) & 0xffff0000u;  // rne bf16, kept in top half
        ub = (ub + 0x7fffu + ((ub >> 16) & 1u)) & 0xffff0000u;
        w[j] = ua | (ub >> 16);
    }

    const float bh_row = bh[tid];

    const int dir = d ? -1 : 1;
    int ta = d ? (TT - 1) : 0;
    const float* __restrict__ gp =
        gi + ((size_t)d * BB + b) * (size_t)TT * GG + (size_t)ta * GG + tid;
    float gnext = *gp;   // gi for step 0

    __syncthreads();

    for (int s = 0; s < TT; ++s) {
        const int cur = s & 1;

        // stage this step's gi (prefetched last iteration) into LDS
        gi_s[tid] = gnext;
        // prefetch next step's gi (full step of latency to cover it)
        if (s + 1 < TT) { gp += (ptrdiff_t)dir * GG; gnext = *gp; }

        // gh[tid] = dot(h, Wh[tid,:]) + bh[tid]  -- weights from registers,
        // h broadcast from LDS (wave-uniform addresses)
        const float4* __restrict__ hv = (const float4*)hbuf[cur];
        float a0 = 0.f, a1 = 0.f, a2 = 0.f, a3 = 0.f;
#pragma unroll
        for (int jj = 0; jj < 64; ++jj) {
            float4 h4 = hv[jj];
            uint32_t wa = w[2 * jj], wb = w[2 * jj + 1];
            a0 = fmaf(__uint_as_float(wa & 0xffff0000u), h4.x, a0);
            a1 = fmaf(__uint_as_float(wa << 16),         h4.y, a1);
            a2 = fmaf(__uint_as_float(wb & 0xffff0000u), h4.z, a2);
            a3 = fmaf(__uint_as_float(wb << 16),         h4.w, a3);
        }
        gh_s[tid] = (a0 + a1) + (a2 + a3) + bh_row;

        __syncthreads();

        if (tid < HH) {
            float ir = gi_s[tid], iz = gi_s[HH + tid], inn = gi_s[2 * HH + tid];
            float hr = gh_s[tid], hz = gh_s[HH + tid], hn = gh_s[2 * HH + tid];
            float r  = sigf(ir + hr);
            float z  = sigf(iz + hz);
            float n  = tanh_fast(inn + r * hn);
            float hp = hbuf[cur][tid];
            float hnew = tanh_fast((1.f - z) * n + z * hp);
            hbuf[cur ^ 1][tid] = hnew;
            out[((size_t)b * TT + ta) * (2 * HH) + d * HH + tid] = hnew;
        }
        ta += dir;
        __syncthreads();
    }
}

// ---------------------------------------------------------------------------
// Fallback scan (ws too small): compute everything on the fly. Unchanged.
// ---------------------------------------------------------------------------
__global__ __launch_bounds__(768) void gru_scan_fallback(
    const float* __restrict__ x,
    const float* __restrict__ h0f, const float* __restrict__ h0b,
    const float* __restrict__ Wif, const float* __restrict__ bif_,
    const float* __restrict__ Whf, const float* __restrict__ bhf,
    const float* __restrict__ Wib, const float* __restrict__ bib_,
    const float* __restrict__ Whb, const float* __restrict__ bhb,
    float* __restrict__ out)
{
    __shared__ __align__(16) float hbuf[2][HH];
    __shared__ float gh_s[GG];
    __shared__ float gi_s[GG];
    __shared__ __align__(16) float xrow[II];

    const int bx  = blockIdx.x;
    const int d   = bx >> 6;
    const int b   = bx & 63;
    const int tid = threadIdx.x;

    const float* __restrict__ Wh = d ? Whb : Whf;
    const float* __restrict__ bh = d ? bhb : bhf;
    const float* __restrict__ Wi = d ? Wib : Wif;
    const float* __restrict__ bi = d ? bib_ : bif_;
    const float* __restrict__ h0 = d ? h0b : h0f;

    if (tid < HH) hbuf[0][tid] = h0[(size_t)b * HH + tid];

    const float bh_row = bh[tid];
    const float bi_row = bi[tid];
    const float4* __restrict__ whr = (const float4*)(Wh + (size_t)tid * II);
    const float4* __restrict__ wir = (const float4*)(Wi + (size_t)tid * II);

    __syncthreads();

    for (int s = 0; s < TT; ++s) {
        const int ta  = d ? (TT - 1 - s) : s;
        const int cur = s & 1;

        if (tid < II) xrow[tid] = x[((size_t)b * TT + ta) * II + tid];
        __syncthreads();

        const float4* hv4 = (const float4*)hbuf[cur];
        float a0 = 0.f, a1 = 0.f, a2 = 0.f, a3 = 0.f;
#pragma unroll 4
        for (int k = 0; k < II / 4; k += 4) {
            float4 w0 = whr[k], w1 = whr[k + 1], w2 = whr[k + 2], w3 = whr[k + 3];
            float4 q0 = hv4[k], q1 = hv4[k + 1], q2 = hv4[k + 2], q3 = hv4[k + 3];
            a0 += w0.x * q0.x + w0.y * q0.y + w0.z * q0.z + w0.w * q0.w;
            a1 += w1.x * q1.x + w1.y * q1.y + w1.z * q1.z + w1.w * q1.w;
            a2 += w2.x * q2.x + w2.y * q2.y + w2.z * q2.z + w2.w * q2.w;
            a3 += w3.x * q3.x + w3.y * q3.y + w3.z * q3.z + w3.w * q3.w;
        }
        gh_s[tid] = (a0 + a1) + (a2 + a3) + bh_row;

        const float4* xv4 = (const float4*)xrow;
        float c0 = 0.f, c1 = 0.f, c2 = 0.f, c3 = 0.f;
#pragma unroll 4
        for (int k = 0; k < II / 4; k += 4) {
            float4 w0 = wir[k], w1 = wir[k + 1], w2 = wir[k + 2], w3 = wir[k + 3];
            float4 q0 = xv4[k], q1 = xv4[k + 1], q2 = xv4[k + 2], q3 = xv4[k + 3];
            c0 += w0.x * q0.x + w0.y * q0.y + w0.z * q0.z + w0.w * q0.w;
            c1 += w1.x * q1.x + w1.y * q1.y + w1.z * q1.z + w1.w * q1.w;
            c2 += w2.x * q2.x + w2.y * q2.y + w2.z * q2.z + w2.w * q2.w;
            c3 += w3.x * q3.x + w3.y * q3.y + w3.z * q3.z + w3.w * q3.w;
        }
        gi_s[tid] = (c0 + c1) + (c2 + c3) + bi_row;
        __syncthreads();

        if (tid < HH) {
            float ir = gi_s[tid], iz = gi_s[HH + tid], inn = gi_s[2 * HH + tid];
            float hr = gh_s[tid], hz = gh_s[HH + tid], hn = gh_s[2 * HH + tid];
            float r  = sigf(ir + hr);
            float z  = sigf(iz + hz);
            float n  = tanh_fast(inn + r * hn);
            float hp = hbuf[cur][tid];
            float hnew = tanh_fast((1.f - z) * n + z * hp);
            hbuf[cur ^ 1][tid] = hnew;
            out[((size_t)b * TT + ta) * (2 * HH) + d * HH + tid] = hnew;
        }
        __syncthreads();
    }
}

// ---------------------------------------------------------------------------
extern "C" void kernel_launch(void* const* d_in, const int* in_sizes, int n_in,
                              void* d_out, int out_size, void* d_ws, size_t ws_size,
                              hipStream_t stream)
{
    const float* x   = (const float*)d_in[0];
    const float* h0f = (const float*)d_in[1];
    const float* h0b = (const float*)d_in[2];
    const float* Wif = (const float*)d_in[3];
    const float* Whf = (const float*)d_in[4];
    const float* bif = (const float*)d_in[5];
    const float* bhf = (const float*)d_in[6];
    const float* Wib = (const float*)d_in[7];
    const float* Whb = (const float*)d_in[8];
    const float* bib = (const float*)d_in[9];
    const float* bhb = (const float*)d_in[10];
    float* out = (float*)d_out;

    const size_t gi_bytes = (size_t)2 * BB * TT * GG * sizeof(float);   // 201,326,592
    const size_t wt_bytes = (size_t)2 * II * GG * sizeof(float);        //   1,572,864

    if (ws_size >= gi_bytes + wt_bytes) {
        float* gi = (float*)d_ws;
        float* wt = (float*)((char*)d_ws + gi_bytes);

        dim3 tg(3, 256, 2);
        transpose_wh<<<tg, 256, 0, stream>>>(Whf, Whb, wt);

        dim3 gg(1024, 12);
        gi_gemm<<<gg, 256, 0, stream>>>(x, Wif, bif, Wib, bib, gi);

        gru_scan_reg<<<128, 768, 0, stream>>>(gi, wt, h0f, h0b, bhf, bhb, out);
    } else {
        gru_scan_fallback<<<128, 768, 0, stream>>>(
            x, h0f, h0b, Wif, bif, Whf, bhf, Wib, bib, Whb, bhb, out);
    }
}

// Round 3
// 1291.783 us; speedup vs baseline: 6.1844x; 6.1844x over previous
//
#include <hip/hip_runtime.h>
#include <cstdint>
#include <cstddef>

#define BB 64
#define TT 512
#define II 256
#define HH 256
#define GG 768   // 3*H

typedef _Float16 f16x2 __attribute__((ext_vector_type(2)));

__device__ __forceinline__ float sigf(float x)       { return 1.f / (1.f + __expf(-x)); }
__device__ __forceinline__ float tanh_fast(float x)  { return 1.f - 2.f / (__expf(2.f * x) + 1.f); }

__device__ __forceinline__ float dot2(uint32_t w, uint32_t h, float acc) {
#if defined(__has_builtin)
#if __has_builtin(__builtin_amdgcn_fdot2)
    return __builtin_amdgcn_fdot2(__builtin_bit_cast(f16x2, w),
                                  __builtin_bit_cast(f16x2, h), acc, false);
#else
    f16x2 a = __builtin_bit_cast(f16x2, w), b = __builtin_bit_cast(f16x2, h);
    return acc + (float)a.x * (float)b.x + (float)a.y * (float)b.y;
#endif
#else
    f16x2 a = __builtin_bit_cast(f16x2, w), b = __builtin_bit_cast(f16x2, h);
    return acc + (float)a.x * (float)b.x + (float)a.y * (float)b.y;
#endif
}

__device__ __forceinline__ uint32_t packf16(float a, float b) {
    f16x2 v; v.x = (_Float16)a; v.y = (_Float16)b;
    return __builtin_bit_cast(uint32_t, v);
}

// ---------------------------------------------------------------------------
// Kernel A: pack Wh into the scan's per-thread coalesced f16x2 layout.
// Layout per direction d (base d*98304 u32):
//   full rows:  wpk[d][j*512 + t]          = f16x2(Wh_d[t][2j], Wh_d[t][2j+1])      j in [0,128)
//   half rows:  wpk[d][65536 + j*512 + t]  = f16x2(Wh_d[512+(t>>1)][128*(t&1)+2j], ... +2j+1)  j in [0,64)
// ---------------------------------------------------------------------------
__global__ void pack_wh(const float* __restrict__ Whf,
                        const float* __restrict__ Whb,
                        uint32_t* __restrict__ wpk)
{
    int idx = blockIdx.x * 256 + threadIdx.x;   // 0 .. 196607
    int d = idx >= 98304;
    int r = idx - d * 98304;
    const float* __restrict__ W = d ? Whb : Whf;
    if (r < 65536) {
        int j = r >> 9, t = r & 511;
        wpk[(size_t)d * 98304 + (size_t)j * 512 + t] =
            packf16(W[(size_t)t * II + 2 * j], W[(size_t)t * II + 2 * j + 1]);
    } else {
        r -= 65536;
        int j = r >> 9, t = r & 511;
        int row = 512 + (t >> 1), ko = 128 * (t & 1);
        wpk[(size_t)d * 98304 + 65536 + (size_t)j * 512 + t] =
            packf16(W[(size_t)row * II + ko + 2 * j], W[(size_t)row * II + ko + 2 * j + 1]);
    }
}

// ---------------------------------------------------------------------------
// Kernel B: gi[d][b][t][g] = x[b,t,:] @ Wi_d[g,:] + bi_d[g]   (unchanged)
// ---------------------------------------------------------------------------
__global__ __launch_bounds__(256) void gi_gemm(
    const float* __restrict__ x,
    const float* __restrict__ Wif, const float* __restrict__ bif,
    const float* __restrict__ Wib, const float* __restrict__ bib,
    float* __restrict__ gi)
{
    const int KC = 16;
    __shared__ float As[64][KC + 1];
    __shared__ float Bs[64][KC + 1];

    const int m0 = blockIdx.x * 64;
    const int n0 = blockIdx.y * 64;
    const int d  = m0 >> 15;
    const float* __restrict__ W    = d ? Wib : Wif;
    const float* __restrict__ bias = d ? bib : bif;

    const int tid = threadIdx.x;
    const int tx = tid & 15, ty = tid >> 4;
    const int xrow = m0 & 32767;

    const int le = tid * 4;
    const int lr = le >> 4;
    const int lk = le & 15;

    float acc[4][4] = {};

    for (int k0 = 0; k0 < II; k0 += KC) {
        float4 av = *(const float4*)&x[(size_t)(xrow + lr) * II + (k0 + lk)];
        float4 bv = *(const float4*)&W[(size_t)(n0 + lr) * II + (k0 + lk)];
        As[lr][lk + 0] = av.x; As[lr][lk + 1] = av.y; As[lr][lk + 2] = av.z; As[lr][lk + 3] = av.w;
        Bs[lr][lk + 0] = bv.x; Bs[lr][lk + 1] = bv.y; Bs[lr][lk + 2] = bv.z; Bs[lr][lk + 3] = bv.w;
        __syncthreads();
#pragma unroll
        for (int kk = 0; kk < KC; ++kk) {
            float a[4], b[4];
#pragma unroll
            for (int i = 0; i < 4; ++i) a[i] = As[ty * 4 + i][kk];
#pragma unroll
            for (int j = 0; j < 4; ++j) b[j] = Bs[tx * 4 + j][kk];
#pragma unroll
            for (int i = 0; i < 4; ++i)
#pragma unroll
                for (int j = 0; j < 4; ++j) acc[i][j] += a[i] * b[j];
        }
        __syncthreads();
    }

#pragma unroll
    for (int i = 0; i < 4; ++i) {
        float4 o;
        o.x = acc[i][0] + bias[n0 + tx * 4 + 0];
        o.y = acc[i][1] + bias[n0 + tx * 4 + 1];
        o.z = acc[i][2] + bias[n0 + tx * 4 + 2];
        o.w = acc[i][3] + bias[n0 + tx * 4 + 3];
        *(float4*)&gi[(size_t)(m0 + ty * 4 + i) * GG + n0 + tx * 4] = o;
    }
}

// ---------------------------------------------------------------------------
// Kernel C: scan with register-resident f16x2 recurrent weights.
// 512 threads (8 waves, 2/SIMD -> VGPR cap 256). Thread t holds:
//   full gate-row t (128 f16x2 regs) + half of n-row 512+(t>>1) (64 regs).
// h broadcast from LDS (packed f16x2); v_dot2_f32_f16 does 2 MACs/inst.
// ---------------------------------------------------------------------------
__global__ __launch_bounds__(512, 2) void gru_scan_reg2(
    const float* __restrict__ gi,     // [2][B][T][G] fp32
    const uint32_t* __restrict__ wpk,
    const float* __restrict__ h0f, const float* __restrict__ h0b,
    const float* __restrict__ bhf, const float* __restrict__ bhb,
    float* __restrict__ out)
{
    __shared__ uint32_t hpk[2][HH / 2];    // h packed f16x2
    __shared__ float    h32[2][HH];        // h fp32 (for z*h term)
    __shared__ float    ghF[512];          // full-row gh partials (rows 0..511)
    __shared__ float    ghH[512];          // half-row partials for n-rows
    __shared__ float    gis[GG];

    const int bx = blockIdx.x;
    const int d  = bx >> 6;
    const int b  = bx & 63;
    const int t  = threadIdx.x;

    const float* __restrict__ bh = d ? bhb : bhf;
    const float* __restrict__ h0 = d ? h0b : h0f;

    if (t < HH) {
        float hv = h0[(size_t)b * HH + t];
        h32[0][t] = hv;
        ((_Float16*)hpk[0])[t] = (_Float16)hv;
    }

    // ---- load weights into registers (coalesced) ----
    const uint32_t* __restrict__ wp = wpk + (size_t)d * 98304;
    uint32_t wf[128], wh[64];
#pragma unroll
    for (int j = 0; j < 128; ++j) wf[j] = wp[(size_t)j * 512 + t];
#pragma unroll
    for (int j = 0; j < 64; ++j)  wh[j] = wp[65536 + (size_t)j * 512 + t];

    const float bhF = bh[t];
    const float bhN = (t < HH) ? bh[2 * HH + t] : 0.f;

    const int dir = d ? -1 : 1;
    int ta = d ? (TT - 1) : 0;
    const float* __restrict__ gp =
        gi + ((size_t)d * BB + b) * (size_t)TT * GG + (size_t)ta * GG;
    float g0 = gp[t];
    float g1 = (t < HH) ? gp[512 + t] : 0.f;

    __syncthreads();

    for (int s = 0; s < TT; ++s) {
        const int cur = s & 1;

        // stage this step's gi (prefetched) into LDS; prefetch next
        gis[t] = g0;
        if (t < HH) gis[512 + t] = g1;
        if (s + 1 < TT) {
            gp += (ptrdiff_t)dir * GG;
            g0 = gp[t];
            if (t < HH) g1 = gp[512 + t];
        }

        // full-row dot (rows 0..511): uniform broadcast reads of packed h
        const uint4* __restrict__ hv4 = (const uint4*)hpk[cur];
        float a0 = 0.f, a1 = 0.f, a2 = 0.f, a3 = 0.f;
#pragma unroll
        for (int jj = 0; jj < 32; ++jj) {
            uint4 h4 = hv4[jj];
            a0 = dot2(wf[4 * jj + 0], h4.x, a0);
            a1 = dot2(wf[4 * jj + 1], h4.y, a1);
            a2 = dot2(wf[4 * jj + 2], h4.z, a2);
            a3 = dot2(wf[4 * jj + 3], h4.w, a3);
        }
        // half-row dot (n-row 512+(t>>1), k-half t&1)
        const int hbase = (t & 1) * 16;
        float c0 = 0.f, c1 = 0.f, c2 = 0.f, c3 = 0.f;
#pragma unroll
        for (int kk = 0; kk < 16; ++kk) {
            uint4 h4 = hv4[hbase + kk];
            c0 = dot2(wh[4 * kk + 0], h4.x, c0);
            c1 = dot2(wh[4 * kk + 1], h4.y, c1);
            c2 = dot2(wh[4 * kk + 2], h4.z, c2);
            c3 = dot2(wh[4 * kk + 3], h4.w, c3);
        }
        ghF[t] = (a0 + a1) + (a2 + a3) + bhF;
        ghH[t] = (c0 + c1) + (c2 + c3);
        __syncthreads();

        if (t < HH) {
            float ir = gis[t], iz = gis[HH + t], inn = gis[2 * HH + t];
            float hr = ghF[t], hz = ghF[HH + t];
            float hn = ghH[2 * t] + ghH[2 * t + 1] + bhN;
            float r  = sigf(ir + hr);
            float z  = sigf(iz + hz);
            float n  = tanh_fast(inn + r * hn);
            float hp = h32[cur][t];
            float hnew = tanh_fast((1.f - z) * n + z * hp);
            h32[cur ^ 1][t] = hnew;
            ((_Float16*)hpk[cur ^ 1])[t] = (_Float16)hnew;
            out[((size_t)b * TT + ta) * (2 * HH) + d * HH + t] = hnew;
        }
        ta += dir;
        __syncthreads();
    }
}

// ---------------------------------------------------------------------------
// Fallback scan (ws too small): unchanged known-good path.
// ---------------------------------------------------------------------------
__global__ __launch_bounds__(768) void gru_scan_fallback(
    const float* __restrict__ x,
    const float* __restrict__ h0f, const float* __restrict__ h0b,
    const float* __restrict__ Wif, const float* __restrict__ bif_,
    const float* __restrict__ Whf, const float* __restrict__ bhf,
    const float* __restrict__ Wib, const float* __restrict__ bib_,
    const float* __restrict__ Whb, const float* __restrict__ bhb,
    float* __restrict__ out)
{
    __shared__ __align__(16) float hbuf[2][HH];
    __shared__ float gh_s[GG];
    __shared__ float gi_s[GG];
    __shared__ __align__(16) float xrow[II];

    const int bx  = blockIdx.x;
    const int d   = bx >> 6;
    const int b   = bx & 63;
    const int tid = threadIdx.x;

    const float* __restrict__ Wh = d ? Whb : Whf;
    const float* __restrict__ bh = d ? bhb : bhf;
    const float* __restrict__ Wi = d ? Wib : Wif;
    const float* __restrict__ bi = d ? bib_ : bif_;
    const float* __restrict__ h0 = d ? h0b : h0f;

    if (tid < HH) hbuf[0][tid] = h0[(size_t)b * HH + tid];

    const float bh_row = bh[tid];
    const float bi_row = bi[tid];
    const float4* __restrict__ whr = (const float4*)(Wh + (size_t)tid * II);
    const float4* __restrict__ wir = (const float4*)(Wi + (size_t)tid * II);

    __syncthreads();

    for (int s = 0; s < TT; ++s) {
        const int ta  = d ? (TT - 1 - s) : s;
        const int cur = s & 1;

        if (tid < II) xrow[tid] = x[((size_t)b * TT + ta) * II + tid];
        __syncthreads();

        const float4* hv4 = (const float4*)hbuf[cur];
        float a0 = 0.f, a1 = 0.f, a2 = 0.f, a3 = 0.f;
#pragma unroll 4
        for (int k = 0; k < II / 4; k += 4) {
            float4 w0 = whr[k], w1 = whr[k + 1], w2 = whr[k + 2], w3 = whr[k + 3];
            float4 q0 = hv4[k], q1 = hv4[k + 1], q2 = hv4[k + 2], q3 = hv4[k + 3];
            a0 += w0.x * q0.x + w0.y * q0.y + w0.z * q0.z + w0.w * q0.w;
            a1 += w1.x * q1.x + w1.y * q1.y + w1.z * q1.z + w1.w * q1.w;
            a2 += w2.x * q2.x + w2.y * q2.y + w2.z * q2.z + w2.w * q2.w;
            a3 += w3.x * q3.x + w3.y * q3.y + w3.z * q3.z + w3.w * q3.w;
        }
        gh_s[tid] = (a0 + a1) + (a2 + a3) + bh_row;

        const float4* xv4 = (const float4*)xrow;
        float c0 = 0.f, c1 = 0.f, c2 = 0.f, c3 = 0.f;
#pragma unroll 4
        for (int k = 0; k < II / 4; k += 4) {
            float4 w0 = wir[k], w1 = wir[k + 1], w2 = wir[k + 2], w3 = wir[k + 3];
            float4 q0 = xv4[k], q1 = xv4[k + 1], q2 = xv4[k + 2], q3 = xv4[k + 3];
            c0 += w0.x * q0.x + w0.y * q0.y + w0.z * q0.z + w0.w * q0.w;
            c1 += w1.x * q1.x + w1.y * q1.y + w1.z * q1.z + w1.w * q1.w;
            c2 += w2.x * q2.x + w2.y * q2.y + w2.z * q2.z + w2.w * q2.w;
            c3 += w3.x * q3.x + w3.y * q3.y + w3.z * q3.z + w3.w * q3.w;
        }
        gi_s[tid] = (c0 + c1) + (c2 + c3) + bi_row;
        __syncthreads();

        if (tid < HH) {
            float ir = gi_s[tid], iz = gi_s[HH + tid], inn = gi_s[2 * HH + tid];
            float hr = gh_s[tid], hz = gh_s[HH + tid], hn = gh_s[2 * HH + tid];
            float r  = sigf(ir + hr);
            float z  = sigf(iz + hz);
            float n  = tanh_fast(inn + r * hn);
            float hp = hbuf[cur][tid];
            float hnew = tanh_fast((1.f - z) * n + z * hp);
            hbuf[cur ^ 1][tid] = hnew;
            out[((size_t)b * TT + ta) * (2 * HH) + d * HH + tid] = hnew;
        }
        __syncthreads();
    }
}

// ---------------------------------------------------------------------------
extern "C" void kernel_launch(void* const* d_in, const int* in_sizes, int n_in,
                              void* d_out, int out_size, void* d_ws, size_t ws_size,
                              hipStream_t stream)
{
    const float* x   = (const float*)d_in[0];
    const float* h0f = (const float*)d_in[1];
    const float* h0b = (const float*)d_in[2];
    const float* Wif = (const float*)d_in[3];
    const float* Whf = (const float*)d_in[4];
    const float* bif = (const float*)d_in[5];
    const float* bhf = (const float*)d_in[6];
    const float* Wib = (const float*)d_in[7];
    const float* Whb = (const float*)d_in[8];
    const float* bib = (const float*)d_in[9];
    const float* bhb = (const float*)d_in[10];
    float* out = (float*)d_out;

    const size_t gi_bytes  = (size_t)2 * BB * TT * GG * sizeof(float);  // 201,326,592
    const size_t wpk_bytes = (size_t)2 * 98304 * sizeof(uint32_t);      //     786,432

    if (ws_size >= gi_bytes + wpk_bytes) {
        float*    gi  = (float*)d_ws;
        uint32_t* wpk = (uint32_t*)((char*)d_ws + gi_bytes);

        pack_wh<<<768, 256, 0, stream>>>(Whf, Whb, wpk);

        dim3 gg(1024, 12);
        gi_gemm<<<gg, 256, 0, stream>>>(x, Wif, bif, Wib, bib, gi);

        gru_scan_reg2<<<128, 512, 0, stream>>>(gi, wpk, h0f, h0b, bhf, bhb, out);
    } else {
        gru_scan_fallback<<<128, 768, 0, stream>>>(
            x, h0f, h0b, Wif, bif, Whf, bhf, Wib, bib, Whb, bhb, out);
    }
}

// Round 4
// 1090.872 us; speedup vs baseline: 7.3234x; 1.1842x over previous
//
#include <hip/hip_runtime.h>
#include <cstdint>
#include <cstddef>

#define BB 64
#define TT 512
#define II 256
#define HH 256
#define GG 768   // 3*H

typedef _Float16 f16x2 __attribute__((ext_vector_type(2)));

__device__ __forceinline__ float sigf(float x)       { return 1.f / (1.f + __expf(-x)); }
__device__ __forceinline__ float tanh_fast(float x)  { return 1.f - 2.f / (__expf(2.f * x) + 1.f); }

__device__ __forceinline__ float dot2(uint32_t w, uint32_t h, float acc) {
#if defined(__has_builtin)
#if __has_builtin(__builtin_amdgcn_fdot2)
    return __builtin_amdgcn_fdot2(__builtin_bit_cast(f16x2, w),
                                  __builtin_bit_cast(f16x2, h), acc, false);
#else
    f16x2 a = __builtin_bit_cast(f16x2, w), b = __builtin_bit_cast(f16x2, h);
    return acc + (float)a.x * (float)b.x + (float)a.y * (float)b.y;
#endif
#else
    f16x2 a = __builtin_bit_cast(f16x2, w), b = __builtin_bit_cast(f16x2, h);
    return acc + (float)a.x * (float)b.x + (float)a.y * (float)b.y;
#endif
}

__device__ __forceinline__ uint32_t packf16(float a, float b) {
    f16x2 v; v.x = (_Float16)a; v.y = (_Float16)b;
    return __builtin_bit_cast(uint32_t, v);
}

// ---------------------------------------------------------------------------
// Kernel A: pack Wh for the k-split scan layout.
// Thread t of the scan owns chunk c = t&3 (k in [c*64, c*64+64)) of rows
// r(t,j) = j*128 + (t>>2), j = 0..5.  Weight reg wf[j*32+m] = f16x2 pair
// (Wh[r][c*64+2m], Wh[r][c*64+2m+1]).  Global layout: wpk[d][jm*512 + t].
// ---------------------------------------------------------------------------
__global__ void pack_wh(const float* __restrict__ Whf,
                        const float* __restrict__ Whb,
                        uint32_t* __restrict__ wpk)
{
    int idx = blockIdx.x * 256 + threadIdx.x;   // 0 .. 196607
    int d = idx >= 98304;
    int u = idx - d * 98304;                    // 0 .. 98303
    int t  = u & 511;
    int jm = u >> 9;                            // 0 .. 191
    int j = jm >> 5, m = jm & 31;
    int r = j * 128 + (t >> 2);
    int c = t & 3;
    const float* __restrict__ W = d ? Whb : Whf;
    const float* base = &W[(size_t)r * II + c * 64 + 2 * m];
    wpk[(size_t)d * 98304 + (size_t)jm * 512 + t] = packf16(base[0], base[1]);
}

// ---------------------------------------------------------------------------
// Kernel B: gi[d][b][t][g] = x[b,t,:] @ Wi_d[g,:] + bi_d[g]   (unchanged)
// ---------------------------------------------------------------------------
__global__ __launch_bounds__(256) void gi_gemm(
    const float* __restrict__ x,
    const float* __restrict__ Wif, const float* __restrict__ bif,
    const float* __restrict__ Wib, const float* __restrict__ bib,
    float* __restrict__ gi)
{
    const int KC = 16;
    __shared__ float As[64][KC + 1];
    __shared__ float Bs[64][KC + 1];

    const int m0 = blockIdx.x * 64;
    const int n0 = blockIdx.y * 64;
    const int d  = m0 >> 15;
    const float* __restrict__ W    = d ? Wib : Wif;
    const float* __restrict__ bias = d ? bib : bif;

    const int tid = threadIdx.x;
    const int tx = tid & 15, ty = tid >> 4;
    const int xrow = m0 & 32767;

    const int le = tid * 4;
    const int lr = le >> 4;
    const int lk = le & 15;

    float acc[4][4] = {};

    for (int k0 = 0; k0 < II; k0 += KC) {
        float4 av = *(const float4*)&x[(size_t)(xrow + lr) * II + (k0 + lk)];
        float4 bv = *(const float4*)&W[(size_t)(n0 + lr) * II + (k0 + lk)];
        As[lr][lk + 0] = av.x; As[lr][lk + 1] = av.y; As[lr][lk + 2] = av.z; As[lr][lk + 3] = av.w;
        Bs[lr][lk + 0] = bv.x; Bs[lr][lk + 1] = bv.y; Bs[lr][lk + 2] = bv.z; Bs[lr][lk + 3] = bv.w;
        __syncthreads();
#pragma unroll
        for (int kk = 0; kk < KC; ++kk) {
            float a[4], b[4];
#pragma unroll
            for (int i = 0; i < 4; ++i) a[i] = As[ty * 4 + i][kk];
#pragma unroll
            for (int j = 0; j < 4; ++j) b[j] = Bs[tx * 4 + j][kk];
#pragma unroll
            for (int i = 0; i < 4; ++i)
#pragma unroll
                for (int j = 0; j < 4; ++j) acc[i][j] += a[i] * b[j];
        }
        __syncthreads();
    }

#pragma unroll
    for (int i = 0; i < 4; ++i) {
        float4 o;
        o.x = acc[i][0] + bias[n0 + tx * 4 + 0];
        o.y = acc[i][1] + bias[n0 + tx * 4 + 1];
        o.z = acc[i][2] + bias[n0 + tx * 4 + 2];
        o.w = acc[i][3] + bias[n0 + tx * 4 + 3];
        *(float4*)&gi[(size_t)(m0 + ty * 4 + i) * GG + n0 + tx * 4] = o;
    }
}

// ---------------------------------------------------------------------------
// Kernel C: k-split scan.  512 threads (8 waves, 2/SIMD -> VGPR cap 256).
// Thread t: chunk c=t&3 of rows {j*128+(t>>2)}, j=0..5 -> 192 f16x2 regs.
// Per step each thread reads only its 128 B h-chunk (8 uint4, padded layout,
// bank-disjoint), does 192 dot2, writes 6 stride-1 partials.  Update threads
// (t<256) sum each row's 4 partials via one float4 read.  h repacked to f16x2
// dwords via shfl (no sub-dword LDS writes).
// ---------------------------------------------------------------------------
__global__ __launch_bounds__(512, 2) void gru_scan_reg3(
    const float* __restrict__ gi,     // [2][B][T][G] fp32
    const uint32_t* __restrict__ wpk,
    const float* __restrict__ h0f, const float* __restrict__ h0b,
    const float* __restrict__ bhf, const float* __restrict__ bhb,
    float* __restrict__ out)
{
    __shared__ __align__(16) uint32_t hpk[2][4 * 36];  // 4 chunks, 32 u32 + 4 pad each
    __shared__ __align__(16) float    h32[2][HH];
    __shared__ __align__(16) float    part[3072];      // [row][4] partials
    __shared__ __align__(16) float    gis[GG];

    const int bx = blockIdx.x;
    const int d  = bx >> 6;
    const int b  = bx & 63;
    const int t  = threadIdx.x;

    const float* __restrict__ bh = d ? bhb : bhf;
    const float* __restrict__ h0 = d ? h0b : h0f;

    // ---- init h (fp32 + packed f16x2 via shfl pairing) ----
    if (t < HH) {
        float hv = h0[(size_t)b * HH + t];
        h32[0][t] = hv;
        float hv1 = __shfl_down(hv, 1);
        if (!(t & 1)) {
            int dw = t >> 1;                       // dword index 0..127
            hpk[0][(dw >> 5) * 36 + (dw & 31)] = packf16(hv, hv1);
        }
    }

    // ---- weights into registers (coalesced) ----
    const uint32_t* __restrict__ wp = wpk + (size_t)d * 98304;
    uint32_t wf[192];
#pragma unroll
    for (int jm = 0; jm < 192; ++jm) wf[jm] = wp[(size_t)jm * 512 + t];

    float bhr = 0.f, bhz = 0.f, bhn = 0.f;
    if (t < HH) { bhr = bh[t]; bhz = bh[HH + t]; bhn = bh[2 * HH + t]; }

    const int dir = d ? -1 : 1;
    int ta = d ? (TT - 1) : 0;
    const float* __restrict__ gp =
        gi + ((size_t)d * BB + b) * (size_t)TT * GG + (size_t)ta * GG;
    float g0 = gp[t];
    float g1 = (t < HH) ? gp[512 + t] : 0.f;

    const int c = t & 3;

    __syncthreads();

    for (int s = 0; s < TT; ++s) {
        const int cur = s & 1;

        // stage this step's gi (prefetched) into LDS; prefetch next
        gis[t] = g0;
        if (t < HH) gis[512 + t] = g1;
        if (s + 1 < TT) {
            gp += (ptrdiff_t)dir * GG;
            g0 = gp[t];
            if (t < HH) g1 = gp[512 + t];
        }

        // ---- dot phase: 8 uint4 h reads, 192 dot2 into 6 accumulators ----
        const uint32_t* __restrict__ hb = &hpk[cur][c * 36];
        float acc[6] = {0.f, 0.f, 0.f, 0.f, 0.f, 0.f};
#pragma unroll
        for (int q = 0; q < 8; ++q) {
            uint4 h4 = *(const uint4*)&hb[q * 4];
#pragma unroll
            for (int j = 0; j < 6; ++j) {
                acc[j] = dot2(wf[j * 32 + q * 4 + 0], h4.x, acc[j]);
                acc[j] = dot2(wf[j * 32 + q * 4 + 1], h4.y, acc[j]);
                acc[j] = dot2(wf[j * 32 + q * 4 + 2], h4.z, acc[j]);
                acc[j] = dot2(wf[j * 32 + q * 4 + 3], h4.w, acc[j]);
            }
        }
        // part[row][chunk] with row=j*128+(t>>2), chunk=t&3  ==  part[j*512+t]
#pragma unroll
        for (int j = 0; j < 6; ++j) part[j * 512 + t] = acc[j];

        __syncthreads();

        // ---- update phase (t < 256) ----
        if (t < HH) {
            float4 p0 = *(const float4*)&part[4 * t];           // row t       (r)
            float4 p1 = *(const float4*)&part[1024 + 4 * t];    // row 256+t   (z)
            float4 p2 = *(const float4*)&part[2048 + 4 * t];    // row 512+t   (n)
            float hr = (p0.x + p0.y) + (p0.z + p0.w) + bhr;
            float hz = (p1.x + p1.y) + (p1.z + p1.w) + bhz;
            float hn = (p2.x + p2.y) + (p2.z + p2.w) + bhn;
            float ir = gis[t], iz = gis[HH + t], inn = gis[2 * HH + t];
            float r  = sigf(ir + hr);
            float z  = sigf(iz + hz);
            float n  = tanh_fast(inn + r * hn);
            float hp = h32[cur][t];
            float hnew = tanh_fast((1.f - z) * n + z * hp);
            h32[cur ^ 1][t] = hnew;
            out[((size_t)b * TT + ta) * (2 * HH) + d * HH + t] = hnew;
            float ho = __shfl_down(hnew, 1);
            if (!(t & 1)) {
                int dw = t >> 1;
                hpk[cur ^ 1][(dw >> 5) * 36 + (dw & 31)] = packf16(hnew, ho);
            }
        }
        ta += dir;
        __syncthreads();
    }
}

// ---------------------------------------------------------------------------
// Fallback scan (ws too small): unchanged known-good path.
// ---------------------------------------------------------------------------
__global__ __launch_bounds__(768) void gru_scan_fallback(
    const float* __restrict__ x,
    const float* __restrict__ h0f, const float* __restrict__ h0b,
    const float* __restrict__ Wif, const float* __restrict__ bif_,
    const float* __restrict__ Whf, const float* __restrict__ bhf,
    const float* __restrict__ Wib, const float* __restrict__ bib_,
    const float* __restrict__ Whb, const float* __restrict__ bhb,
    float* __restrict__ out)
{
    __shared__ __align__(16) float hbuf[2][HH];
    __shared__ float gh_s[GG];
    __shared__ float gi_s[GG];
    __shared__ __align__(16) float xrow[II];

    const int bx  = blockIdx.x;
    const int d   = bx >> 6;
    const int b   = bx & 63;
    const int tid = threadIdx.x;

    const float* __restrict__ Wh = d ? Whb : Whf;
    const float* __restrict__ bh = d ? bhb : bhf;
    const float* __restrict__ Wi = d ? Wib : Wif;
    const float* __restrict__ bi = d ? bib_ : bif_;
    const float* __restrict__ h0 = d ? h0b : h0f;

    if (tid < HH) hbuf[0][tid] = h0[(size_t)b * HH + tid];

    const float bh_row = bh[tid];
    const float bi_row = bi[tid];
    const float4* __restrict__ whr = (const float4*)(Wh + (size_t)tid * II);
    const float4* __restrict__ wir = (const float4*)(Wi + (size_t)tid * II);

    __syncthreads();

    for (int s = 0; s < TT; ++s) {
        const int ta  = d ? (TT - 1 - s) : s;
        const int cur = s & 1;

        if (tid < II) xrow[tid] = x[((size_t)b * TT + ta) * II + tid];
        __syncthreads();

        const float4* hv4 = (const float4*)hbuf[cur];
        float a0 = 0.f, a1 = 0.f, a2 = 0.f, a3 = 0.f;
#pragma unroll 4
        for (int k = 0; k < II / 4; k += 4) {
            float4 w0 = whr[k], w1 = whr[k + 1], w2 = whr[k + 2], w3 = whr[k + 3];
            float4 q0 = hv4[k], q1 = hv4[k + 1], q2 = hv4[k + 2], q3 = hv4[k + 3];
            a0 += w0.x * q0.x + w0.y * q0.y + w0.z * q0.z + w0.w * q0.w;
            a1 += w1.x * q1.x + w1.y * q1.y + w1.z * q1.z + w1.w * q1.w;
            a2 += w2.x * q2.x + w2.y * q2.y + w2.z * q2.z + w2.w * q2.w;
            a3 += w3.x * q3.x + w3.y * q3.y + w3.z * q3.z + w3.w * q3.w;
        }
        gh_s[tid] = (a0 + a1) + (a2 + a3) + bh_row;

        const float4* xv4 = (const float4*)xrow;
        float c0 = 0.f, c1 = 0.f, c2 = 0.f, c3 = 0.f;
#pragma unroll 4
        for (int k = 0; k < II / 4; k += 4) {
            float4 w0 = wir[k], w1 = wir[k + 1], w2 = wir[k + 2], w3 = wir[k + 3];
            float4 q0 = xv4[k], q1 = xv4[k + 1], q2 = xv4[k + 2], q3 = xv4[k + 3];
            c0 += w0.x * q0.x + w0.y * q0.y + w0.z * q0.z + w0.w * q0.w;
            c1 += w1.x * q1.x + w1.y * q1.y + w1.z * q1.z + w1.w * q1.w;
            c2 += w2.x * q2.x + w2.y * q2.y + w2.z * q2.z + w2.w * q2.w;
            c3 += w3.x * q3.x + w3.y * q3.y + w3.z * q3.z + w3.w * q3.w;
        }
        gi_s[tid] = (c0 + c1) + (c2 + c3) + bi_row;
        __syncthreads();

        if (tid < HH) {
            float ir = gi_s[tid], iz = gi_s[HH + tid], inn = gi_s[2 * HH + tid];
            float hr = gh_s[tid], hz = gh_s[HH + tid], hn = gh_s[2 * HH + tid];
            float r  = sigf(ir + hr);
            float z  = sigf(iz + hz);
            float n  = tanh_fast(inn + r * hn);
            float hp = hbuf[cur][tid];
            float hnew = tanh_fast((1.f - z) * n + z * hp);
            hbuf[cur ^ 1][tid] = hnew;
            out[((size_t)b * TT + ta) * (2 * HH) + d * HH + tid] = hnew;
        }
        __syncthreads();
    }
}

// ---------------------------------------------------------------------------
extern "C" void kernel_launch(void* const* d_in, const int* in_sizes, int n_in,
                              void* d_out, int out_size, void* d_ws, size_t ws_size,
                              hipStream_t stream)
{
    const float* x   = (const float*)d_in[0];
    const float* h0f = (const float*)d_in[1];
    const float* h0b = (const float*)d_in[2];
    const float* Wif = (const float*)d_in[3];
    const float* Whf = (const float*)d_in[4];
    const float* bif = (const float*)d_in[5];
    const float* bhf = (const float*)d_in[6];
    const float* Wib = (const float*)d_in[7];
    const float* Whb = (const float*)d_in[8];
    const float* bib = (const float*)d_in[9];
    const float* bhb = (const float*)d_in[10];
    float* out = (float*)d_out;

    const size_t gi_bytes  = (size_t)2 * BB * TT * GG * sizeof(float);  // 201,326,592
    const size_t wpk_bytes = (size_t)2 * 98304 * sizeof(uint32_t);      //     786,432

    if (ws_size >= gi_bytes + wpk_bytes) {
        float*    gi  = (float*)d_ws;
        uint32_t* wpk = (uint32_t*)((char*)d_ws + gi_bytes);

        pack_wh<<<768, 256, 0, stream>>>(Whf, Whb, wpk);

        dim3 gg(1024, 12);
        gi_gemm<<<gg, 256, 0, stream>>>(x, Wif, bif, Wib, bib, gi);

        gru_scan_reg3<<<128, 512, 0, stream>>>(gi, wpk, h0f, h0b, bhf, bhb, out);
    } else {
        gru_scan_fallback<<<128, 768, 0, stream>>>(
            x, h0f, h0b, Wif, bif, Whf, bhf, Wib, bib, Whb, bhb, out);
    }
}

// Round 5
// 726.736 us; speedup vs baseline: 10.9928x; 1.5011x over previous
//
#include <hip/hip_runtime.h>
#include <cstdint>
#include <cstddef>

#define BB 64
#define TT 512
#define II 256
#define HH 256
#define GG 768   // 3*H

typedef _Float16 f16x2 __attribute__((ext_vector_type(2)));
typedef _Float16 f16x8 __attribute__((ext_vector_type(8)));
typedef float    f32x4 __attribute__((ext_vector_type(4)));

__device__ __forceinline__ float sigf(float x)       { return 1.f / (1.f + __expf(-x)); }
__device__ __forceinline__ float tanh_fast(float x)  { return 1.f - 2.f / (__expf(2.f * x) + 1.f); }

__device__ __forceinline__ float dot2(uint32_t w, uint32_t h, float acc) {
#if defined(__has_builtin)
#if __has_builtin(__builtin_amdgcn_fdot2)
    return __builtin_amdgcn_fdot2(__builtin_bit_cast(f16x2, w),
                                  __builtin_bit_cast(f16x2, h), acc, false);
#else
    f16x2 a = __builtin_bit_cast(f16x2, w), b = __builtin_bit_cast(f16x2, h);
    return acc + (float)a.x * (float)b.x + (float)a.y * (float)b.y;
#endif
#else
    f16x2 a = __builtin_bit_cast(f16x2, w), b = __builtin_bit_cast(f16x2, h);
    return acc + (float)a.x * (float)b.x + (float)a.y * (float)b.y;
#endif
}

__device__ __forceinline__ uint32_t packf16(float a, float b) {
    f16x2 v; v.x = (_Float16)a; v.y = (_Float16)b;
    return __builtin_bit_cast(uint32_t, v);
}

// ---------------------------------------------------------------------------
// Kernel A: pack Wh for the k-split scan layout (unchanged from R4).
// ---------------------------------------------------------------------------
__global__ void pack_wh(const float* __restrict__ Whf,
                        const float* __restrict__ Whb,
                        uint32_t* __restrict__ wpk)
{
    int idx = blockIdx.x * 256 + threadIdx.x;   // 0 .. 196607
    int d = idx >= 98304;
    int u = idx - d * 98304;                    // 0 .. 98303
    int t  = u & 511;
    int jm = u >> 9;                            // 0 .. 191
    int j = jm >> 5, m = jm & 31;
    int r = j * 128 + (t >> 2);
    int c = t & 3;
    const float* __restrict__ W = d ? Whb : Whf;
    const float* base = &W[(size_t)r * II + c * 64 + 2 * m];
    wpk[(size_t)d * 98304 + (size_t)jm * 512 + t] = packf16(base[0], base[1]);
}

// ---------------------------------------------------------------------------
// Kernel B (new): MFMA f16 GEMM for gi.
// gi[m][n] = x[m&32767, :] . W_d[n, :] + bias_d[n],  m = d*32768 + b*512 + t
// M = 65536, N = 768, K = 256.  Tile 64x64, BK = 64, 256 threads (4 waves).
// Wave w computes rows [16w,16w+16) x all 64 cols: 4 accumulators.
// fp32 -> f16 conversion happens during LDS staging (no extra workspace).
// LDS layout [k>>3][row][k&7]: fragment reads are aligned ds_read_b128,
// 2-way bank aliasing only (free).
// Fragment layouts (gfx950 16x16x32 f16):
//   A: lane l, elem e -> A[l&15][8*(l>>4)+e]
//   B: lane l, elem e -> B[8*(l>>4)+e][l&15]   (B[k][n] = W[n][k])
//   C/D: reg r, lane l -> D[(l>>4)*4 + r][l&15]   [verified m89]
// ---------------------------------------------------------------------------
__global__ __launch_bounds__(256) void gi_gemm_mfma(
    const float* __restrict__ x,
    const float* __restrict__ Wif, const float* __restrict__ bif,
    const float* __restrict__ Wib, const float* __restrict__ bib,
    float* __restrict__ gi)
{
    __shared__ __align__(16) _Float16 Asm[8][64][8];   // 8 KB
    __shared__ __align__(16) _Float16 Bsm[8][64][8];   // 8 KB

    const int ntile = blockIdx.x % 12;
    const int mtile = blockIdx.x / 12;
    const int m0 = mtile * 64;
    const int n0 = ntile * 64;
    const int d  = m0 >> 15;
    const int xrow0 = m0 & 32767;
    const float* __restrict__ W    = d ? Wib : Wif;
    const float* __restrict__ bias = d ? bib : bif;

    const int tid  = threadIdx.x;
    const int w    = tid >> 6;
    const int lane = tid & 63;
    const int lr   = lane & 15;
    const int lk8  = (lane >> 4);       // k-group (of 8) offset within 32

    f32x4 acc[4] = {};

    // staging map: thread handles row = tid>>2, 16 consecutive k (2 f16x8 stores)
    const int srow = tid >> 2;
    const int scol = (tid & 3) * 16;

    for (int k0 = 0; k0 < II; k0 += 64) {
        const float* ap = &x[(size_t)(xrow0 + srow) * II + k0 + scol];
        const float* bp = &W[(size_t)(n0 + srow)   * II + k0 + scol];
#pragma unroll
        for (int half = 0; half < 2; ++half) {
            float4 a0 = *(const float4*)(ap + 8 * half);
            float4 a1 = *(const float4*)(ap + 8 * half + 4);
            float4 b0 = *(const float4*)(bp + 8 * half);
            float4 b1 = *(const float4*)(bp + 8 * half + 4);
            f16x8 av, bv;
            av[0] = (_Float16)a0.x; av[1] = (_Float16)a0.y;
            av[2] = (_Float16)a0.z; av[3] = (_Float16)a0.w;
            av[4] = (_Float16)a1.x; av[5] = (_Float16)a1.y;
            av[6] = (_Float16)a1.z; av[7] = (_Float16)a1.w;
            bv[0] = (_Float16)b0.x; bv[1] = (_Float16)b0.y;
            bv[2] = (_Float16)b0.z; bv[3] = (_Float16)b0.w;
            bv[4] = (_Float16)b1.x; bv[5] = (_Float16)b1.y;
            bv[6] = (_Float16)b1.z; bv[7] = (_Float16)b1.w;
            *(f16x8*)&Asm[scol / 8 + half][srow][0] = av;
            *(f16x8*)&Bsm[scol / 8 + half][srow][0] = bv;
        }
        __syncthreads();

#pragma unroll
        for (int kk = 0; kk < 2; ++kk) {            // two K=32 chunks in BK=64
            const int kb = kk * 4 + lk8;            // k-group (of 8) index 0..7
            f16x8 af = *(const f16x8*)&Asm[kb][16 * w + lr][0];
#pragma unroll
            for (int j = 0; j < 4; ++j) {
                f16x8 bf = *(const f16x8*)&Bsm[kb][16 * j + lr][0];
                acc[j] = __builtin_amdgcn_mfma_f32_16x16x32_f16(af, bf, acc[j], 0, 0, 0);
            }
        }
        __syncthreads();
    }

    // epilogue: D[(l>>4)*4 + r][l&15] ; add bias, store fp32
    const int rbase = m0 + 16 * w + (lane >> 4) * 4;
#pragma unroll
    for (int j = 0; j < 4; ++j) {
        const int col = n0 + 16 * j + lr;
        const float bcol = bias[col];
#pragma unroll
        for (int r = 0; r < 4; ++r) {
            gi[(size_t)(rbase + r) * GG + col] = acc[j][r] + bcol;
        }
    }
}

// ---------------------------------------------------------------------------
// Kernel C: k-split scan (unchanged from R4).
// ---------------------------------------------------------------------------
__global__ __launch_bounds__(512, 2) void gru_scan_reg3(
    const float* __restrict__ gi,     // [2][B][T][G] fp32
    const uint32_t* __restrict__ wpk,
    const float* __restrict__ h0f, const float* __restrict__ h0b,
    const float* __restrict__ bhf, const float* __restrict__ bhb,
    float* __restrict__ out)
{
    __shared__ __align__(16) uint32_t hpk[2][4 * 36];  // 4 chunks, 32 u32 + 4 pad each
    __shared__ __align__(16) float    h32[2][HH];
    __shared__ __align__(16) float    part[3072];      // [row][4] partials
    __shared__ __align__(16) float    gis[GG];

    const int bx = blockIdx.x;
    const int d  = bx >> 6;
    const int b  = bx & 63;
    const int t  = threadIdx.x;

    const float* __restrict__ bh = d ? bhb : bhf;
    const float* __restrict__ h0 = d ? h0b : h0f;

    if (t < HH) {
        float hv = h0[(size_t)b * HH + t];
        h32[0][t] = hv;
        float hv1 = __shfl_down(hv, 1);
        if (!(t & 1)) {
            int dw = t >> 1;                       // dword index 0..127
            hpk[0][(dw >> 5) * 36 + (dw & 31)] = packf16(hv, hv1);
        }
    }

    const uint32_t* __restrict__ wp = wpk + (size_t)d * 98304;
    uint32_t wf[192];
#pragma unroll
    for (int jm = 0; jm < 192; ++jm) wf[jm] = wp[(size_t)jm * 512 + t];

    float bhr = 0.f, bhz = 0.f, bhn = 0.f;
    if (t < HH) { bhr = bh[t]; bhz = bh[HH + t]; bhn = bh[2 * HH + t]; }

    const int dir = d ? -1 : 1;
    int ta = d ? (TT - 1) : 0;
    const float* __restrict__ gp =
        gi + ((size_t)d * BB + b) * (size_t)TT * GG + (size_t)ta * GG;
    float g0 = gp[t];
    float g1 = (t < HH) ? gp[512 + t] : 0.f;

    const int c = t & 3;

    __syncthreads();

    for (int s = 0; s < TT; ++s) {
        const int cur = s & 1;

        gis[t] = g0;
        if (t < HH) gis[512 + t] = g1;
        if (s + 1 < TT) {
            gp += (ptrdiff_t)dir * GG;
            g0 = gp[t];
            if (t < HH) g1 = gp[512 + t];
        }

        const uint32_t* __restrict__ hb = &hpk[cur][c * 36];
        float acc[6] = {0.f, 0.f, 0.f, 0.f, 0.f, 0.f};
#pragma unroll
        for (int q = 0; q < 8; ++q) {
            uint4 h4 = *(const uint4*)&hb[q * 4];
#pragma unroll
            for (int j = 0; j < 6; ++j) {
                acc[j] = dot2(wf[j * 32 + q * 4 + 0], h4.x, acc[j]);
                acc[j] = dot2(wf[j * 32 + q * 4 + 1], h4.y, acc[j]);
                acc[j] = dot2(wf[j * 32 + q * 4 + 2], h4.z, acc[j]);
                acc[j] = dot2(wf[j * 32 + q * 4 + 3], h4.w, acc[j]);
            }
        }
#pragma unroll
        for (int j = 0; j < 6; ++j) part[j * 512 + t] = acc[j];

        __syncthreads();

        if (t < HH) {
            float4 p0 = *(const float4*)&part[4 * t];           // row t       (r)
            float4 p1 = *(const float4*)&part[1024 + 4 * t];    // row 256+t   (z)
            float4 p2 = *(const float4*)&part[2048 + 4 * t];    // row 512+t   (n)
            float hr = (p0.x + p0.y) + (p0.z + p0.w) + bhr;
            float hz = (p1.x + p1.y) + (p1.z + p1.w) + bhz;
            float hn = (p2.x + p2.y) + (p2.z + p2.w) + bhn;
            float ir = gis[t], iz = gis[HH + t], inn = gis[2 * HH + t];
            float r  = sigf(ir + hr);
            float z  = sigf(iz + hz);
            float n  = tanh_fast(inn + r * hn);
            float hp = h32[cur][t];
            float hnew = tanh_fast((1.f - z) * n + z * hp);
            h32[cur ^ 1][t] = hnew;
            out[((size_t)b * TT + ta) * (2 * HH) + d * HH + t] = hnew;
            float ho = __shfl_down(hnew, 1);
            if (!(t & 1)) {
                int dw = t >> 1;
                hpk[cur ^ 1][(dw >> 5) * 36 + (dw & 31)] = packf16(hnew, ho);
            }
        }
        ta += dir;
        __syncthreads();
    }
}

// ---------------------------------------------------------------------------
// Fallback scan (ws too small): unchanged known-good path.
// ---------------------------------------------------------------------------
__global__ __launch_bounds__(768) void gru_scan_fallback(
    const float* __restrict__ x,
    const float* __restrict__ h0f, const float* __restrict__ h0b,
    const float* __restrict__ Wif, const float* __restrict__ bif_,
    const float* __restrict__ Whf, const float* __restrict__ bhf,
    const float* __restrict__ Wib, const float* __restrict__ bib_,
    const float* __restrict__ Whb, const float* __restrict__ bhb,
    float* __restrict__ out)
{
    __shared__ __align__(16) float hbuf[2][HH];
    __shared__ float gh_s[GG];
    __shared__ float gi_s[GG];
    __shared__ __align__(16) float xrow[II];

    const int bx  = blockIdx.x;
    const int d   = bx >> 6;
    const int b   = bx & 63;
    const int tid = threadIdx.x;

    const float* __restrict__ Wh = d ? Whb : Whf;
    const float* __restrict__ bh = d ? bhb : bhf;
    const float* __restrict__ Wi = d ? Wib : Wif;
    const float* __restrict__ bi = d ? bib_ : bif_;
    const float* __restrict__ h0 = d ? h0b : h0f;

    if (tid < HH) hbuf[0][tid] = h0[(size_t)b * HH + tid];

    const float bh_row = bh[tid];
    const float bi_row = bi[tid];
    const float4* __restrict__ whr = (const float4*)(Wh + (size_t)tid * II);
    const float4* __restrict__ wir = (const float4*)(Wi + (size_t)tid * II);

    __syncthreads();

    for (int s = 0; s < TT; ++s) {
        const int ta  = d ? (TT - 1 - s) : s;
        const int cur = s & 1;

        if (tid < II) xrow[tid] = x[((size_t)b * TT + ta) * II + tid];
        __syncthreads();

        const float4* hv4 = (const float4*)hbuf[cur];
        float a0 = 0.f, a1 = 0.f, a2 = 0.f, a3 = 0.f;
#pragma unroll 4
        for (int k = 0; k < II / 4; k += 4) {
            float4 w0 = whr[k], w1 = whr[k + 1], w2 = whr[k + 2], w3 = whr[k + 3];
            float4 q0 = hv4[k], q1 = hv4[k + 1], q2 = hv4[k + 2], q3 = hv4[k + 3];
            a0 += w0.x * q0.x + w0.y * q0.y + w0.z * q0.z + w0.w * q0.w;
            a1 += w1.x * q1.x + w1.y * q1.y + w1.z * q1.z + w1.w * q1.w;
            a2 += w2.x * q2.x + w2.y * q2.y + w2.z * q2.z + w2.w * q2.w;
            a3 += w3.x * q3.x + w3.y * q3.y + w3.z * q3.z + w3.w * q3.w;
        }
        gh_s[tid] = (a0 + a1) + (a2 + a3) + bh_row;

        const float4* xv4 = (const float4*)xrow;
        float c0 = 0.f, c1 = 0.f, c2 = 0.f, c3 = 0.f;
#pragma unroll 4
        for (int k = 0; k < II / 4; k += 4) {
            float4 w0 = wir[k], w1 = wir[k + 1], w2 = wir[k + 2], w3 = wir[k + 3];
            float4 q0 = xv4[k], q1 = xv4[k + 1], q2 = xv4[k + 2], q3 = xv4[k + 3];
            c0 += w0.x * q0.x + w0.y * q0.y + w0.z * q0.z + w0.w * q0.w;
            c1 += w1.x * q1.x + w1.y * q1.y + w1.z * q1.z + w1.w * q1.w;
            c2 += w2.x * q2.x + w2.y * q2.y + w2.z * q2.z + w2.w * q2.w;
            c3 += w3.x * q3.x + w3.y * q3.y + w3.z * q3.z + w3.w * q3.w;
        }
        gi_s[tid] = (c0 + c1) + (c2 + c3) + bi_row;
        __syncthreads();

        if (tid < HH) {
            float ir = gi_s[tid], iz = gi_s[HH + tid], inn = gi_s[2 * HH + tid];
            float hr = gh_s[tid], hz = gh_s[HH + tid], hn = gh_s[2 * HH + tid];
            float r  = sigf(ir + hr);
            float z  = sigf(iz + hz);
            float n  = tanh_fast(inn + r * hn);
            float hp = hbuf[cur][tid];
            float hnew = tanh_fast((1.f - z) * n + z * hp);
            hbuf[cur ^ 1][tid] = hnew;
            out[((size_t)b * TT + ta) * (2 * HH) + d * HH + tid] = hnew;
        }
        __syncthreads();
    }
}

// ---------------------------------------------------------------------------
extern "C" void kernel_launch(void* const* d_in, const int* in_sizes, int n_in,
                              void* d_out, int out_size, void* d_ws, size_t ws_size,
                              hipStream_t stream)
{
    const float* x   = (const float*)d_in[0];
    const float* h0f = (const float*)d_in[1];
    const float* h0b = (const float*)d_in[2];
    const float* Wif = (const float*)d_in[3];
    const float* Whf = (const float*)d_in[4];
    const float* bif = (const float*)d_in[5];
    const float* bhf = (const float*)d_in[6];
    const float* Wib = (const float*)d_in[7];
    const float* Whb = (const float*)d_in[8];
    const float* bib = (const float*)d_in[9];
    const float* bhb = (const float*)d_in[10];
    float* out = (float*)d_out;

    const size_t gi_bytes  = (size_t)2 * BB * TT * GG * sizeof(float);  // 201,326,592
    const size_t wpk_bytes = (size_t)2 * 98304 * sizeof(uint32_t);      //     786,432

    if (ws_size >= gi_bytes + wpk_bytes) {
        float*    gi  = (float*)d_ws;
        uint32_t* wpk = (uint32_t*)((char*)d_ws + gi_bytes);

        pack_wh<<<768, 256, 0, stream>>>(Whf, Whb, wpk);

        gi_gemm_mfma<<<12288, 256, 0, stream>>>(x, Wif, bif, Wib, bib, gi);

        gru_scan_reg3<<<128, 512, 0, stream>>>(gi, wpk, h0f, h0b, bhf, bhb, out);
    } else {
        gru_scan_fallback<<<128, 768, 0, stream>>>(
            x, h0f, h0b, Wif, bif, Whf, bhf, Wib, bib, Whb, bhb, out);
    }
}